// Round 4
// baseline (474.622 us; speedup 1.0000x reference)
//
#include <hip/hip_runtime.h>
#include <math.h>

// Problem constants (from reference setup_inputs)
#define BSZ   64
#define NROWS 4096          // H*W
#define CCH   128           // channels
#define NC4   32            // channels / 4

typedef float vf4 __attribute__((ext_vector_type(4)));

__device__ __forceinline__ float dot4(float4 a, float4 b) {
    return a.x*b.x + a.y*b.y + a.z*b.z + a.w*b.w;
}

// =====================================================================
// Per-batch barrier: 16 sibling blocks rendezvous on one counter.
// Release fetch_add publishes prior stores (agent-scope release =>
// L2 writeback on chiplet parts); acquire load + fence invalidates.
// WATCHDOG: spin is bounded -- a logic error produces a wrong answer
// (bench mismatch), never a container-killing hang.
// =====================================================================
__device__ __forceinline__ void batch_barrier(int* __restrict__ ctr,
                                              int target, int t) {
    __syncthreads();                      // all block stores issued
    if (t == 0) {
        __threadfence();                  // agent release: wb dirty L2
        __hip_atomic_fetch_add(ctr, 1, __ATOMIC_RELEASE,
                               __HIP_MEMORY_SCOPE_AGENT);
        int spins = 0;
        while (__hip_atomic_load(ctr, __ATOMIC_ACQUIRE,
                                 __HIP_MEMORY_SCOPE_AGENT) < target) {
            __builtin_amdgcn_s_sleep(2);
            if (++spins > (1 << 22)) break;   // ~0.2 s cap: fail-visible
        }
        __threadfence();                  // agent acquire: inv L1/L2
    }
    __syncthreads();                      // rest of block waits on lane 0
}

// =====================================================================
// Fused kernel: 1024 blocks x 256 threads, block = (b = blk>>4, sub),
// owns rows [sub*256, sub*256+256) of batch b in all three phases.
// Coop launch guarantees co-residency; sync is per-batch (16 blocks),
// NOT grid-wide (round-1 grid.sync cost ~200 us -- avoided).
// __launch_bounds__(256,4) => VGPR<=128; LDS ~18 KB => 8 blocks/CU cap.
// =====================================================================
#define RPB 256   // rows per block

__global__ __launch_bounds__(256, 4) void k_fused(
        const float4* __restrict__ x,
        const float*  __restrict__ beta,
        const float*  __restrict__ gamma,
        float*        __restrict__ part,     // [1024][128]
        float*        __restrict__ varpart,  // [1024]
        int*          __restrict__ ctrs,     // [64][32]
        float4*       __restrict__ out) {
    const int blk = blockIdx.x;
    const int b   = blk >> 4;
    const int sub = blk & 15;
    const int t   = threadIdx.x;

    __shared__ float4 lds4[256];   // phase-1 partials (dead after phase 1)
    __shared__ float  sm[128];
    __shared__ float4 mvs[32];     // normalized mean   (phase2 -> phase3)
    __shared__ float4 bvs[32];     // beta              (phase2 -> phase3)
    __shared__ float2 red2[256];
    __shared__ float  redh[256];
    __shared__ float4 rowp[RPB];   // per-row (fac, h, tc, pb)
    __shared__ float  rowS[RPB];   // per-row s_m
    __shared__ float4 abcd[RPB];   // per-row output coefficients (phase 3)

    const float4* xb = x + ((size_t)b * NROWS + sub * RPB) * NC4;

    // ---------------- phase 1: per-block channel sums ----------------
    {
        const int c4  = t & 31;
        const int grp = t >> 5;
        float4 acc = make_float4(0.f, 0.f, 0.f, 0.f);
        #pragma unroll 4
        for (int r = grp; r < RPB; r += 8) {
            float4 v = xb[(size_t)r * NC4 + c4];
            acc.x += v.x; acc.y += v.y; acc.z += v.z; acc.w += v.w;
        }
        lds4[t] = acc;
        __syncthreads();
        if (t < 32) {
            float4 s = lds4[t];
            #pragma unroll
            for (int k = 1; k < 8; ++k) {
                float4 v = lds4[t + 32 * k];
                s.x += v.x; s.y += v.y; s.z += v.z; s.w += v.w;
            }
            ((float4*)(part + (size_t)blk * CCH))[t] = make_float4(s.x, s.y, s.z, s.w);
        }
    }
    batch_barrier(&ctrs[b * 32], 16, t);

    // ------------- phase 2: mean + per-row params + var partial -------------
    float m = 0.f, bc = 0.f;
    if (t < 128) {
        float s = 0.f;
        #pragma unroll
        for (int k = 0; k < 16; ++k)
            s += part[(size_t)((b << 4) + k) * CCH + t];
        m  = s * (1.0f / (float)NROWS);
        bc = beta[t];
        sm[t] = m;
    }
    red2[t] = make_float2(m * m, bc * m);
    __syncthreads();
    #pragma unroll
    for (int s = 128; s > 0; s >>= 1) {
        if (t < s) { red2[t].x += red2[t + s].x; red2[t].y += red2[t + s].y; }
        __syncthreads();
    }
    const float smm = red2[0].x, sbm = red2[0].y;
    const float m0  = sm[0];
    const float val = fmaf(2.f * m0, m0, -smm);                 // -linner(m,m)
    const float inv = __builtin_amdgcn_rsqf(fmaxf(val, 1e-8f));
    const float mean0   = m0 * inv;
    const float inv1pm0 = __builtin_amdgcn_rcpf(1.0f + mean0);
    const float b0  = beta[0];
    const float lbm = (sbm - 2.f * b0 * m0) * inv;              // linner(beta, mean)
    if (t < 128) {
        ((float*)mvs)[t] = sm[t] * inv;
        ((float*)bvs)[t] = bc;
    }
    __syncthreads();

    {
        const int lane = t & 63, wave = t >> 6;
        const int q    = lane >> 2;      // row-within-16
        const int ql   = lane & 3;       // chunk phase
        const int srcl = lane & ~3;      // quad base lane
        float nsum = 0.f;

        #pragma unroll
        for (int o = 0; o < 4; ++o) {
            const int lrow = o * 64 + wave * 16 + q;
            const float4* xr = xb + (size_t)lrow * NC4;

            // c = 0 peeled to capture channel 0
            float4 xv = xr[ql];
            float4 mv = mvs[ql];
            float4 bv = bvs[ql];
            float x00 = xv.x;            // valid on ql==0 lanes
            float d = dot4(xv, mv);
            float e = dot4(xv, bv);
            #pragma unroll
            for (int c = 1; c < 8; ++c) {
                int c4i = 4 * c + ql;    // quad covers 64B contiguous
                xv = xr[c4i];
                mv = mvs[c4i];
                bv = bvs[c4i];
                d = fmaf(xv.x, mv.x, fmaf(xv.y, mv.y, fmaf(xv.z, mv.z, fmaf(xv.w, mv.w, d))));
                e = fmaf(xv.x, bv.x, fmaf(xv.y, bv.y, fmaf(xv.z, bv.z, fmaf(xv.w, bv.w, e))));
            }
            d += __shfl_xor(d, 1);  e += __shfl_xor(e, 1);
            d += __shfl_xor(d, 2);  e += __shfl_xor(e, 2);
            float x0 = __shfl(x00, srcl);

            float alpha = fmaxf(fmaf(2.f * mean0, x0, -d), 1.0f + 1e-7f);
            float a2m1  = fmaxf(fmaf(alpha, alpha, -1.f), 1e-8f);   // linner(u,u)
            float sq    = sqrtf(a2m1);
            float h     = __logf(alpha + sq);                        // acosh(alpha)
            float fac   = h * __builtin_amdgcn_rcpf(sq);
            float u0    = fmaf(-alpha, mean0, x0);
            float tc    = fac * u0 * inv1pm0;
            float s_m   = fmaf(fac, alpha, tc);    // x_T = fac*x - s_m*mean - tc*e0
            float lbx   = fmaf(-2.f * b0, x0, e);  // linner(beta, x)
            float pb    = fmaf(fac, lbx, fmaf(-s_m, lbm, tc * b0)); // linner(beta, x_T)
            if (ql == 0) {
                rowp[lrow] = make_float4(fac, h, tc, pb);
                rowS[lrow] = s_m;
            }
            nsum += 0.25f * h;           // h identical across quad; 0.25f exact
        }
        redh[t] = nsum;
    }
    __syncthreads();
    #pragma unroll
    for (int s = 128; s > 0; s >>= 1) {
        if (t < s) redh[t] += redh[t + s];
        __syncthreads();
    }
    if (t == 0) varpart[blk] = redh[0];
    batch_barrier(&ctrs[b * 32 + 16], 16, t);

    // ---------------- phase 3: output ----------------
    {
        float vsum = 0.f;
        #pragma unroll
        for (int k = 0; k < 16; ++k) vsum += varpart[(b << 4) + k];  // uniform
        const float scale = gamma[0] * __builtin_amdgcn_rcpf(
                                vsum * (1.0f / (float)NROWS) + 1e-5f);
        const float invb  = __builtin_amdgcn_rcpf(1.0f + b0);

        // per-row coefficients once (not x32 per channel lane):
        // note fac*sq == h by construction, so nu = scale*h.
        {
            float4 rp = rowp[t];
            float fac = rp.x, h = rp.y, tcv = rp.z, pb = rp.w;
            float s_m = rowS[t];
            float F   = scale * fac;
            float TCv = scale * tcv;
            float SMv = scale * s_m;
            float nu  = fmaxf(scale * h, 1e-4f);
            float PT  = scale * pb * invb;

            float ee = __expf(nu);
            float ei = __builtin_amdgcn_rcpf(ee);
            float ch = 0.5f * (ee + ei);
            float so = 0.5f * (ee - ei) * __builtin_amdgcn_rcpf(nu);

            abcd[t] = make_float4(so * F,                 // A
                                  -so * SMv,              // B
                                  fmaf(so, PT, ch),       // C
                                  so * (PT - TCv));       // D
        }
        __syncthreads();

        const int c4  = t & 31;
        const int grp = t >> 5;
        const float4 mv = mvs[c4];
        const float4 bv = bvs[c4];
        float4* ob = out + ((size_t)b * NROWS + sub * RPB) * NC4;

        #pragma unroll 4
        for (int r = grp; r < RPB; r += 8) {
            float4 xv = xb[(size_t)r * NC4 + c4];
            float4 cf = abcd[r];                  // LDS broadcast within group
            float A = cf.x, B = cf.y, C = cf.z, D = cf.w;

            vf4 ov;
            ov.x = fmaf(A, xv.x, fmaf(B, mv.x, C * bv.x));
            ov.y = fmaf(A, xv.y, fmaf(B, mv.y, C * bv.y));
            ov.z = fmaf(A, xv.z, fmaf(B, mv.z, C * bv.z));
            ov.w = fmaf(A, xv.w, fmaf(B, mv.w, C * bv.w));
            if (c4 == 0) ov.x += D;
            __builtin_nontemporal_store(ov, (vf4*)&ob[(size_t)r * NC4 + c4]);
        }
    }
}

// =====================================================================
// Fallback: proven round-2 3-kernel path (verbatim), used only if the
// cooperative launch is rejected.
// =====================================================================
#define BPB1 32
#define RPB1 (NROWS/BPB1)

__global__ __launch_bounds__(256) void k_sum(const float4* __restrict__ x,
                                             float* __restrict__ part) {
    const int gb  = blockIdx.x;
    const int b   = gb >> 5;
    const int blk = gb & 31;
    const int t   = threadIdx.x;
    const int c4  = t & 31;
    const int grp = t >> 5;
    const float4* xb = x + ((size_t)b * NROWS + blk * RPB1) * NC4;

    float4 acc = make_float4(0.f, 0.f, 0.f, 0.f);
    #pragma unroll 4
    for (int r = grp; r < RPB1; r += 8) {
        float4 v = xb[(size_t)r * NC4 + c4];
        acc.x += v.x; acc.y += v.y; acc.z += v.z; acc.w += v.w;
    }
    __shared__ float4 lds[256];
    lds[t] = acc;
    __syncthreads();
    if (t < 32) {
        float4 s = lds[t];
        #pragma unroll
        for (int k = 1; k < 8; ++k) {
            float4 v = lds[t + 32 * k];
            s.x += v.x; s.y += v.y; s.z += v.z; s.w += v.w;
        }
        ((float4*)(part + (size_t)gb * CCH))[t] = make_float4(s.x, s.y, s.z, s.w);
    }
}

__global__ __launch_bounds__(256) void k_rows(const float4* __restrict__ x,
                                              const float* __restrict__ part,
                                              const float* __restrict__ beta,
                                              float* __restrict__ mean,
                                              float* __restrict__ varpart,
                                              float4* __restrict__ rowpg) {
    const int blk = blockIdx.x;
    const int b   = blk >> 4;
    const int sub = blk & 15;
    const int t   = threadIdx.x;

    __shared__ float  sm[128];
    __shared__ float4 mvs[32];
    __shared__ float4 bvs[32];
    __shared__ float2 red2[256];
    __shared__ float  redh[256];

    float m = 0.f, bc = 0.f;
    if (t < 128) {
        float s = 0.f;
        #pragma unroll
        for (int k = 0; k < 32; ++k)
            s += part[(size_t)((b << 5) + k) * CCH + t];
        m  = s * (1.0f / (float)NROWS);
        bc = beta[t];
        sm[t] = m;
    }
    red2[t] = make_float2(m * m, bc * m);
    __syncthreads();
    #pragma unroll
    for (int s = 128; s > 0; s >>= 1) {
        if (t < s) { red2[t].x += red2[t + s].x; red2[t].y += red2[t + s].y; }
        __syncthreads();
    }
    const float smm = red2[0].x, sbm = red2[0].y;
    const float m0  = sm[0];
    const float val = fmaf(2.f * m0, m0, -smm);
    const float inv = __builtin_amdgcn_rsqf(fmaxf(val, 1e-8f));
    const float mean0   = m0 * inv;
    const float inv1pm0 = __builtin_amdgcn_rcpf(1.0f + mean0);
    const float b0  = beta[0];
    const float lbm = (sbm - 2.f * b0 * m0) * inv;
    if (t < 128) {
        float mc = sm[t] * inv;
        ((float*)mvs)[t] = mc;
        ((float*)bvs)[t] = bc;
        if (sub == 0) mean[b * CCH + t] = mc;
    }
    __syncthreads();

    const int lane = t & 63, wave = t >> 6;
    const int q    = lane >> 2;
    const int ql   = lane & 3;
    const int srcl = lane & ~3;
    float nsum = 0.f;

    #pragma unroll
    for (int o = 0; o < 4; ++o) {
        const int row = sub * 256 + o * 64 + wave * 16 + q;
        const float4* xr = x + ((size_t)b * NROWS + row) * NC4;

        float4 xv = xr[ql];
        float4 mv = mvs[ql];
        float4 bv = bvs[ql];
        float x00 = xv.x;
        float d = dot4(xv, mv);
        float e = dot4(xv, bv);
        #pragma unroll
        for (int c = 1; c < 8; ++c) {
            int c4i = 4 * c + ql;
            xv = xr[c4i];
            mv = mvs[c4i];
            bv = bvs[c4i];
            d = fmaf(xv.x, mv.x, fmaf(xv.y, mv.y, fmaf(xv.z, mv.z, fmaf(xv.w, mv.w, d))));
            e = fmaf(xv.x, bv.x, fmaf(xv.y, bv.y, fmaf(xv.z, bv.z, fmaf(xv.w, bv.w, e))));
        }
        d += __shfl_xor(d, 1);  e += __shfl_xor(e, 1);
        d += __shfl_xor(d, 2);  e += __shfl_xor(e, 2);
        float x0 = __shfl(x00, srcl);

        float alpha = fmaxf(fmaf(2.f * mean0, x0, -d), 1.0f + 1e-7f);
        float a2m1  = fmaxf(fmaf(alpha, alpha, -1.f), 1e-8f);
        float sq    = sqrtf(a2m1);
        float h     = __logf(alpha + sq);
        float fac   = h * __builtin_amdgcn_rcpf(sq);
        float u0    = fmaf(-alpha, mean0, x0);
        float tc    = fac * u0 * inv1pm0;
        float s_m   = fmaf(fac, alpha, tc);
        float lbx   = fmaf(-2.f * b0, x0, e);
        float pb    = fmaf(fac, lbx, fmaf(-s_m, lbm, tc * b0));
        if (ql == 0) rowpg[(size_t)b * NROWS + row] = make_float4(fac, alpha, tc, pb);
        nsum += 0.25f * h;
    }

    redh[t] = nsum;
    __syncthreads();
    #pragma unroll
    for (int s = 128; s > 0; s >>= 1) {
        if (t < s) redh[t] += redh[t + s];
        __syncthreads();
    }
    if (t == 0) varpart[blk] = redh[0];
}

__global__ __launch_bounds__(256) void k_out(const float4* __restrict__ x,
                                             const float* __restrict__ mean,
                                             const float* __restrict__ varpart,
                                             const float* __restrict__ beta,
                                             const float* __restrict__ gamma,
                                             const float4* __restrict__ rowpg,
                                             float4* __restrict__ out) {
    const int b   = blockIdx.x / BPB1;
    const int blk = blockIdx.x % BPB1;
    const int t   = threadIdx.x;
    const int c4  = t & 31;
    const int grp = t >> 5;

    const float* meanb = mean + b * CCH;
    float4 mv = ((const float4*)meanb)[c4];
    float4 bv = ((const float4*)beta)[c4];
    float  b0 = beta[0];
    float  invb = __builtin_amdgcn_rcpf(1.0f + b0);

    float vsum = 0.f;
    #pragma unroll
    for (int k = 0; k < 16; ++k) vsum += varpart[(b << 4) + k];
    float scale = gamma[0] * __builtin_amdgcn_rcpf(
                      vsum * (1.0f / (float)NROWS) + 1e-5f);

    const float4* xb = x + (size_t)b * NROWS * NC4;
    float4*       ob = out + (size_t)b * NROWS * NC4;
    const int row0 = blk * RPB1;

    #pragma unroll 4
    for (int r = row0 + grp; r < row0 + RPB1; r += 8) {
        float4 xv = xb[(size_t)r * NC4 + c4];
        float4 rp = rowpg[(size_t)b * NROWS + r];
        float fac = rp.x, alpha = rp.y, tcv = rp.z, pb = rp.w;

        float F   = scale * fac;
        float TCv = scale * tcv;
        float SM  = fmaf(F, alpha, TCv);
        float sq  = sqrtf(fmaxf(fmaf(alpha, alpha, -1.f), 1e-8f));
        float nu  = fmaxf(scale * (fac * sq), 1e-4f);
        float PT  = scale * pb * invb;

        float ee = __expf(nu);
        float ei = __builtin_amdgcn_rcpf(ee);
        float ch = 0.5f * (ee + ei);
        float so = 0.5f * (ee - ei) * __builtin_amdgcn_rcpf(nu);

        float A = so * F;
        float B = -so * SM;
        float C = fmaf(so, PT, ch);
        float D = so * (PT - TCv);

        vf4 ov;
        ov.x = fmaf(A, xv.x, fmaf(B, mv.x, C * bv.x));
        ov.y = fmaf(A, xv.y, fmaf(B, mv.y, C * bv.y));
        ov.z = fmaf(A, xv.z, fmaf(B, mv.z, C * bv.z));
        ov.w = fmaf(A, xv.w, fmaf(B, mv.w, C * bv.w));
        if (c4 == 0) ov.x += D;
        __builtin_nontemporal_store(ov, (vf4*)&ob[(size_t)r * NC4 + c4]);
    }
}

// ---------- launch ----------
extern "C" void kernel_launch(void* const* d_in, const int* in_sizes, int n_in,
                              void* d_out, int out_size, void* d_ws, size_t ws_size,
                              hipStream_t stream) {
    const float4* x     = (const float4*)d_in[0];
    const float*  beta  = (const float*)d_in[1];
    const float*  gamma = (const float*)d_in[2];
    float4*       out   = (float4*)d_out;

    char* wsb = (char*)d_ws;
    // Fused-path layout (paths are mutually exclusive, so they may overlap
    // fallback arrays; total footprint <= 6 MB either way):
    //   ctrs    [64][32] ints : 8 KB   @ 0   (memset each replay)
    //   part    [1024][128]   : 512 KB @ 8 KB
    //   varpart [1024]        : 4 KB   @ 8 KB + 512 KB
    int*   ctrs     = (int*)(wsb);
    float* partF    = (float*)(wsb + 8192);
    float* varpartF = (float*)(wsb + 8192 + 524288);

    hipMemsetAsync(ctrs, 0, 64 * 32 * sizeof(int), stream);

    void* args[7] = { (void*)&x, (void*)&beta, (void*)&gamma,
                      (void*)&partF, (void*)&varpartF, (void*)&ctrs,
                      (void*)&out };
    hipError_t err = hipLaunchCooperativeKernel((const void*)k_fused,
                                                dim3(1024), dim3(256),
                                                args, 0, stream);
    if (err != hipSuccess) {
        // Fallback: proven round-2 3-kernel path.
        //   part    [2048][128] : 1 MB  @ 8 KB
        //   varpart [1024]      : 4 KB  @ 8 KB + 1 MB
        //   mean    [64][128]   : 32 KB @ 8 KB + 1 MB + 4 KB
        //   rowp    [64*4096]x4 : 4 MB  @ 2 MB   (16B aligned)
        float*  part    = (float*)(wsb + 8192);
        float*  varpart = (float*)(wsb + 8192 + (1 << 20));
        float*  mean    = (float*)(wsb + 8192 + (1 << 20) + 4096);
        float4* rowpg   = (float4*)(wsb + (2 << 20));

        k_sum<<<dim3(BSZ * BPB1), dim3(256), 0, stream>>>(x, part);
        k_rows<<<dim3(1024), dim3(256), 0, stream>>>(
            x, part, beta, mean, varpart, rowpg);
        k_out<<<dim3(BSZ * BPB1), dim3(256), 0, stream>>>(
            x, mean, varpart, beta, gamma, rowpg, out);
    }
}

// Round 5
// 277.191 us; speedup vs baseline: 1.7123x; 1.7123x over previous
//
#include <hip/hip_runtime.h>
#include <math.h>

// Problem constants (from reference setup_inputs)
#define BSZ   64
#define NROWS 4096          // H*W
#define CCH   128           // channels
#define NC4   32            // channels / 4

typedef float vf4 __attribute__((ext_vector_type(4)));

__device__ __forceinline__ float dot4(float4 a, float4 b) {
    return a.x*b.x + a.y*b.y + a.z*b.z + a.w*b.w;
}

// =====================================================================
// kernel 1: per-block channel partial sums -> plain stores (no atomics,
// no memset). 2048 blocks (32 per batch) x 256 threads. Pure HBM stream:
// unroll 8 => 8 outstanding 16B loads per lane to cover ~900cy latency.
// =====================================================================
#define BPB1 32
#define RPB1 (NROWS/BPB1)   // 128 rows per block

__global__ __launch_bounds__(256) void k_sum(const float4* __restrict__ x,
                                             float* __restrict__ part) {
    const int gb  = blockIdx.x;          // 0..2047
    const int b   = gb >> 5;
    const int blk = gb & 31;
    const int t   = threadIdx.x;
    const int c4  = t & 31;
    const int grp = t >> 5;
    const float4* xb = x + ((size_t)b * NROWS + blk * RPB1) * NC4;

    float4 acc = make_float4(0.f, 0.f, 0.f, 0.f);
    #pragma unroll 8
    for (int r = grp; r < RPB1; r += 8) {
        float4 v = xb[(size_t)r * NC4 + c4];
        acc.x += v.x; acc.y += v.y; acc.z += v.z; acc.w += v.w;
    }
    __shared__ float4 lds[256];
    lds[t] = acc;
    __syncthreads();
    if (t < 32) {
        float4 s = lds[t];
        #pragma unroll
        for (int k = 1; k < 8; ++k) {
            float4 v = lds[t + 32 * k];
            s.x += v.x; s.y += v.y; s.z += v.z; s.w += v.w;
        }
        ((float4*)(part + (size_t)gb * CCH))[t] = make_float4(s.x, s.y, s.z, s.w);
    }
}

// =====================================================================
// kernel 2: mean (from partials) + per-row params + variance partials.
// 1024 blocks (16 per batch, 256 rows each) x 256 threads.
// mvs/bvs hoisted to registers (loop-invariant across the o-loop).
// =====================================================================
__global__ __launch_bounds__(256) void k_rows(const float4* __restrict__ x,
                                              const float* __restrict__ part,
                                              const float* __restrict__ beta,
                                              float* __restrict__ mean,
                                              float* __restrict__ varpart,
                                              float4* __restrict__ rowp) {
    const int blk = blockIdx.x;          // 0..1023
    const int b   = blk >> 4;            // 16 blocks per batch
    const int sub = blk & 15;
    const int t   = threadIdx.x;

    __shared__ float  sm[128];           // raw mean m (pre-normalization)
    __shared__ float4 mvs[32];           // normalized mean
    __shared__ float4 bvs[32];           // beta
    __shared__ float2 red2[256];
    __shared__ float  redh[256];

    float m = 0.f, bc = 0.f;
    if (t < 128) {
        float s = 0.f;
        #pragma unroll
        for (int k = 0; k < 32; ++k)
            s += part[(size_t)((b << 5) + k) * CCH + t];
        m  = s * (1.0f / (float)NROWS);
        bc = beta[t];
        sm[t] = m;
    }
    red2[t] = make_float2(m * m, bc * m);
    __syncthreads();
    #pragma unroll
    for (int s = 128; s > 0; s >>= 1) {
        if (t < s) { red2[t].x += red2[t + s].x; red2[t].y += red2[t + s].y; }
        __syncthreads();
    }
    const float smm = red2[0].x, sbm = red2[0].y;
    const float m0  = sm[0];
    const float val = fmaf(2.f * m0, m0, -smm);                 // -linner(m,m)
    const float inv = __builtin_amdgcn_rsqf(fmaxf(val, 1e-8f));
    const float mean0   = m0 * inv;
    const float inv1pm0 = __builtin_amdgcn_rcpf(1.0f + mean0);
    const float b0  = beta[0];
    const float lbm = (sbm - 2.f * b0 * m0) * inv;              // linner(beta, mean)
    if (t < 128) {
        float mc = sm[t] * inv;
        ((float*)mvs)[t] = mc;
        ((float*)bvs)[t] = bc;
        if (sub == 0) mean[b * CCH + t] = mc;
    }
    __syncthreads();

    const int lane = t & 63, wave = t >> 6;
    const int q    = lane >> 2;      // row-within-16
    const int ql   = lane & 3;       // chunk phase
    const int srcl = lane & ~3;      // quad base lane

    // hoist mean/beta fragments to registers (invariant across o-loop)
    float4 mvr[8], bvr[8];
    #pragma unroll
    for (int c = 0; c < 8; ++c) {
        mvr[c] = mvs[4 * c + ql];
        bvr[c] = bvs[4 * c + ql];
    }

    float nsum = 0.f;
    #pragma unroll
    for (int o = 0; o < 4; ++o) {
        const int row = sub * 256 + o * 64 + wave * 16 + q;
        const float4* xr = x + ((size_t)b * NROWS + row) * NC4;

        // c = 0 peeled to capture channel 0
        float4 xv = xr[ql];
        float x00 = xv.x;            // valid on ql==0 lanes
        float d = dot4(xv, mvr[0]);
        float e = dot4(xv, bvr[0]);
        #pragma unroll
        for (int c = 1; c < 8; ++c) {
            xv = xr[4 * c + ql];     // quad covers 64B contiguous
            d = fmaf(xv.x, mvr[c].x, fmaf(xv.y, mvr[c].y,
                fmaf(xv.z, mvr[c].z, fmaf(xv.w, mvr[c].w, d))));
            e = fmaf(xv.x, bvr[c].x, fmaf(xv.y, bvr[c].y,
                fmaf(xv.z, bvr[c].z, fmaf(xv.w, bvr[c].w, e))));
        }
        d += __shfl_xor(d, 1);  e += __shfl_xor(e, 1);
        d += __shfl_xor(d, 2);  e += __shfl_xor(e, 2);
        float x0 = __shfl(x00, srcl);

        float alpha = fmaxf(fmaf(2.f * mean0, x0, -d), 1.0f + 1e-7f);
        float a2m1  = fmaxf(fmaf(alpha, alpha, -1.f), 1e-8f);   // linner(u,u) = a^2-1
        float sq    = sqrtf(a2m1);
        float h     = __logf(alpha + sq);                        // acosh(alpha)
        float fac   = h * __builtin_amdgcn_rcpf(sq);
        float u0    = fmaf(-alpha, mean0, x0);
        float tc    = fac * u0 * inv1pm0;
        float s_m   = fmaf(fac, alpha, tc);    // x_T = fac*x - s_m*mean - tc*e0
        float lbx   = fmaf(-2.f * b0, x0, e);  // linner(beta, x)
        float pb    = fmaf(fac, lbx, fmaf(-s_m, lbm, tc * b0)); // linner(beta, x_T)
        if (ql == 0) rowp[(size_t)b * NROWS + row] = make_float4(fac, alpha, tc, pb);
        nsum += 0.25f * h;           // h identical across quad; 0.25f exact
    }

    redh[t] = nsum;
    __syncthreads();
    #pragma unroll
    for (int s = 128; s > 0; s >>= 1) {
        if (t < s) redh[t] += redh[t + s];
        __syncthreads();
    }
    if (t == 0) varpart[blk] = redh[0];   // plain store, no atomic
}

// =====================================================================
// kernel 3: output. Stage per-row coefficients A,B,C,D ONCE (128 rows,
// one per thread) into LDS, then the stream loop is pure
// {load x, LDS broadcast, 3 FMA, NT store}. Transcendentals drop 32x.
// 2048 blocks (32 per batch, 128 rows each) x 256 threads.
// =====================================================================
#define BPB3 32
#define RPB3 (NROWS/BPB3)   // 128

__global__ __launch_bounds__(256) void k_out(const float4* __restrict__ x,
                                             const float* __restrict__ mean,
                                             const float* __restrict__ varpart,
                                             const float* __restrict__ beta,
                                             const float* __restrict__ gamma,
                                             const float4* __restrict__ rowp,
                                             float4* __restrict__ out) {
    const int b   = blockIdx.x / BPB3;
    const int blk = blockIdx.x % BPB3;
    const int t   = threadIdx.x;
    const int c4  = t & 31;
    const int grp = t >> 5;
    const int row0 = blk * RPB3;

    __shared__ float4 abcd[RPB3];   // per-row output coefficients

    const float* meanb = mean + b * CCH;
    float4 mv = ((const float4*)meanb)[c4];
    float4 bv = ((const float4*)beta)[c4];
    float  b0 = beta[0];
    float  invb = __builtin_amdgcn_rcpf(1.0f + b0);

    float vsum = 0.f;
    #pragma unroll
    for (int k = 0; k < 16; ++k) vsum += varpart[(b << 4) + k];  // uniform
    float scale = gamma[0] * __builtin_amdgcn_rcpf(
                      vsum * (1.0f / (float)NROWS) + 1e-5f);

    // ---- stage: one row per thread (t < 128) ----
    if (t < RPB3) {
        float4 rp = rowp[(size_t)b * NROWS + row0 + t];
        float fac = rp.x, alpha = rp.y, tcv = rp.z, pb = rp.w;

        float F   = scale * fac;
        float TCv = scale * tcv;
        float SM  = fmaf(F, alpha, TCv);                 // scale * s_m
        float sq  = sqrtf(fmaxf(fmaf(alpha, alpha, -1.f), 1e-8f));
        float nu  = fmaxf(scale * (fac * sq), 1e-4f);    // = sqrt(clip(linner,1e-8))
        float PT  = scale * pb * invb;

        float ee = __expf(nu);
        float ei = __builtin_amdgcn_rcpf(ee);
        float ch = 0.5f * (ee + ei);
        float so = 0.5f * (ee - ei) * __builtin_amdgcn_rcpf(nu);

        abcd[t] = make_float4(so * F,                    // A
                              -so * SM,                  // B
                              fmaf(so, PT, ch),          // C
                              so * (PT - TCv));          // D (ch-0 add)
    }
    __syncthreads();

    const float4* xb = x + (size_t)b * NROWS * NC4;
    float4*       ob = out + (size_t)b * NROWS * NC4;

    #pragma unroll 4
    for (int r = grp; r < RPB3; r += 8) {
        float4 xv = xb[(size_t)(row0 + r) * NC4 + c4];
        float4 cf = abcd[r];                  // LDS broadcast within group
        float A = cf.x, B = cf.y, C = cf.z, D = cf.w;

        vf4 ov;
        ov.x = fmaf(A, xv.x, fmaf(B, mv.x, C * bv.x));
        ov.y = fmaf(A, xv.y, fmaf(B, mv.y, C * bv.y));
        ov.z = fmaf(A, xv.z, fmaf(B, mv.z, C * bv.z));
        ov.w = fmaf(A, xv.w, fmaf(B, mv.w, C * bv.w));
        if (c4 == 0) ov.x += D;
        // non-temporal full-line store: don't evict x from L3
        __builtin_nontemporal_store(ov, (vf4*)&ob[(size_t)(row0 + r) * NC4 + c4]);
    }
}

// ---------- launch ----------
extern "C" void kernel_launch(void* const* d_in, const int* in_sizes, int n_in,
                              void* d_out, int out_size, void* d_ws, size_t ws_size,
                              hipStream_t stream) {
    const float4* x     = (const float4*)d_in[0];
    const float*  beta  = (const float*)d_in[1];
    const float*  gamma = (const float*)d_in[2];
    float4*       out   = (float4*)d_out;

    // Workspace layout (all plain-stored, no memset required):
    //   part    [2048][128] floats : 1 MB     @ 0
    //   varpart [1024] floats      : 4 KB     @ 1 MB
    //   mean    [64][128] floats   : 32 KB    @ 1 MB + 4 KB
    //   rowp    [64*4096] float4   : 4 MB     @ 2 MB (16B aligned)
    char* wsb = (char*)d_ws;
    float*  part    = (float*)(wsb);
    float*  varpart = (float*)(wsb + (1 << 20));
    float*  mean    = (float*)(wsb + (1 << 20) + 4096);
    float4* rowp    = (float4*)(wsb + (2 << 20));

    k_sum<<<dim3(BSZ * BPB1), dim3(256), 0, stream>>>(x, part);
    k_rows<<<dim3(1024), dim3(256), 0, stream>>>(
        x, part, beta, mean, varpart, rowp);
    k_out<<<dim3(BSZ * BPB3), dim3(256), 0, stream>>>(
        x, mean, varpart, beta, gamma, rowp, out);
}

// Round 6
// 276.722 us; speedup vs baseline: 1.7152x; 1.0017x over previous
//
#include <hip/hip_runtime.h>
#include <math.h>

// Problem constants (from reference setup_inputs)
#define BSZ   64
#define NROWS 4096          // H*W
#define CCH   128           // channels
#define NC4   32            // channels / 4

typedef float vf4 __attribute__((ext_vector_type(4)));

__device__ __forceinline__ float dot4(float4 a, float4 b) {
    return a.x*b.x + a.y*b.y + a.z*b.z + a.w*b.w;
}

// =====================================================================
// kernel 1: per-block channel partial sums -> plain stores (no atomics,
// no memset). 2048 blocks (32 per batch) x 256 threads. Pure HBM stream.
// =====================================================================
#define BPB1 32
#define RPB1 (NROWS/BPB1)   // 128 rows per block

__global__ __launch_bounds__(256) void k_sum(const float4* __restrict__ x,
                                             float* __restrict__ part) {
    const int gb  = blockIdx.x;          // 0..2047
    const int b   = gb >> 5;
    const int blk = gb & 31;
    const int t   = threadIdx.x;
    const int c4  = t & 31;
    const int grp = t >> 5;
    const float4* xb = x + ((size_t)b * NROWS + blk * RPB1) * NC4;

    float4 acc = make_float4(0.f, 0.f, 0.f, 0.f);
    #pragma unroll 8
    for (int r = grp; r < RPB1; r += 8) {
        float4 v = xb[(size_t)r * NC4 + c4];
        acc.x += v.x; acc.y += v.y; acc.z += v.z; acc.w += v.w;
    }
    __shared__ float4 lds[256];
    lds[t] = acc;
    __syncthreads();
    if (t < 32) {
        float4 s = lds[t];
        #pragma unroll
        for (int k = 1; k < 8; ++k) {
            float4 v = lds[t + 32 * k];
            s.x += v.x; s.y += v.y; s.z += v.z; s.w += v.w;
        }
        ((float4*)(part + (size_t)gb * CCH))[t] = make_float4(s.x, s.y, s.z, s.w);
    }
}

// =====================================================================
// kernel 2: mean (from partials) + per-row params + variance partials.
// 2048 blocks (32 per batch, 128 rows each) x 256 threads
// => 8 blocks/CU (was 4) to cover L3 read latency with TLP.
// Inner loop reads mean/beta from LDS (R2-verified form, low VGPR).
// =====================================================================
#define BPB2 32
#define RPB2 (NROWS/BPB2)   // 128 rows per block

__global__ __launch_bounds__(256) void k_rows(const float4* __restrict__ x,
                                              const float* __restrict__ part,
                                              const float* __restrict__ beta,
                                              float* __restrict__ mean,
                                              float* __restrict__ varpart,
                                              float4* __restrict__ rowp) {
    const int blk = blockIdx.x;          // 0..2047
    const int b   = blk >> 5;            // 32 blocks per batch
    const int sub = blk & 31;
    const int t   = threadIdx.x;

    __shared__ float  sm[128];           // raw mean m (pre-normalization)
    __shared__ float4 mvs[32];           // normalized mean
    __shared__ float4 bvs[32];           // beta
    __shared__ float2 red2[256];
    __shared__ float  redh[256];

    float m = 0.f, bc = 0.f;
    if (t < 128) {
        float s = 0.f;
        #pragma unroll
        for (int k = 0; k < 32; ++k)
            s += part[(size_t)((b << 5) + k) * CCH + t];
        m  = s * (1.0f / (float)NROWS);
        bc = beta[t];
        sm[t] = m;
    }
    red2[t] = make_float2(m * m, bc * m);
    __syncthreads();
    #pragma unroll
    for (int s = 128; s > 0; s >>= 1) {
        if (t < s) { red2[t].x += red2[t + s].x; red2[t].y += red2[t + s].y; }
        __syncthreads();
    }
    const float smm = red2[0].x, sbm = red2[0].y;
    const float m0  = sm[0];
    const float val = fmaf(2.f * m0, m0, -smm);                 // -linner(m,m)
    const float inv = __builtin_amdgcn_rsqf(fmaxf(val, 1e-8f));
    const float mean0   = m0 * inv;
    const float inv1pm0 = __builtin_amdgcn_rcpf(1.0f + mean0);
    const float b0  = beta[0];
    const float lbm = (sbm - 2.f * b0 * m0) * inv;              // linner(beta, mean)
    if (t < 128) {
        float mc = sm[t] * inv;
        ((float*)mvs)[t] = mc;
        ((float*)bvs)[t] = bc;
        if (sub == 0) mean[b * CCH + t] = mc;
    }
    __syncthreads();

    const int lane = t & 63, wave = t >> 6;
    const int q    = lane >> 2;      // row-within-16
    const int ql   = lane & 3;       // chunk phase
    const int srcl = lane & ~3;      // quad base lane
    float nsum = 0.f;

    #pragma unroll
    for (int o = 0; o < 2; ++o) {
        const int row = sub * RPB2 + o * 64 + wave * 16 + q;
        const float4* xr = x + ((size_t)b * NROWS + row) * NC4;

        // c = 0 peeled to capture channel 0
        float4 xv = xr[ql];
        float4 mv = mvs[ql];
        float4 bv = bvs[ql];
        float x00 = xv.x;            // valid on ql==0 lanes
        float d = dot4(xv, mv);
        float e = dot4(xv, bv);
        #pragma unroll
        for (int c = 1; c < 8; ++c) {
            int c4i = 4 * c + ql;    // quad covers 64B contiguous
            xv = xr[c4i];
            mv = mvs[c4i];
            bv = bvs[c4i];
            d = fmaf(xv.x, mv.x, fmaf(xv.y, mv.y, fmaf(xv.z, mv.z, fmaf(xv.w, mv.w, d))));
            e = fmaf(xv.x, bv.x, fmaf(xv.y, bv.y, fmaf(xv.z, bv.z, fmaf(xv.w, bv.w, e))));
        }
        d += __shfl_xor(d, 1);  e += __shfl_xor(e, 1);
        d += __shfl_xor(d, 2);  e += __shfl_xor(e, 2);
        float x0 = __shfl(x00, srcl);

        float alpha = fmaxf(fmaf(2.f * mean0, x0, -d), 1.0f + 1e-7f);
        float a2m1  = fmaxf(fmaf(alpha, alpha, -1.f), 1e-8f);   // linner(u,u) = a^2-1
        float sq    = sqrtf(a2m1);
        float h     = __logf(alpha + sq);                        // acosh(alpha)
        float fac   = h * __builtin_amdgcn_rcpf(sq);
        float u0    = fmaf(-alpha, mean0, x0);
        float tc    = fac * u0 * inv1pm0;
        float s_m   = fmaf(fac, alpha, tc);    // x_T = fac*x - s_m*mean - tc*e0
        float lbx   = fmaf(-2.f * b0, x0, e);  // linner(beta, x)
        float pb    = fmaf(fac, lbx, fmaf(-s_m, lbm, tc * b0)); // linner(beta, x_T)
        if (ql == 0) rowp[(size_t)b * NROWS + row] = make_float4(fac, alpha, tc, pb);
        nsum += 0.25f * h;           // h identical across quad; 0.25f exact
    }

    redh[t] = nsum;
    __syncthreads();
    #pragma unroll
    for (int s = 128; s > 0; s >>= 1) {
        if (t < s) redh[t] += redh[t + s];
        __syncthreads();
    }
    if (t == 0) varpart[blk] = redh[0];   // plain store, no atomic
}

// =====================================================================
// kernel 3: output. Stage per-row coefficients A,B,C,D ONCE (128 rows,
// one per thread) into LDS, then the stream loop is pure
// {load x, LDS broadcast, 3 FMA, NT store}.
// 2048 blocks (32 per batch, 128 rows each) x 256 threads.
// =====================================================================
#define BPB3 32
#define RPB3 (NROWS/BPB3)   // 128

__global__ __launch_bounds__(256) void k_out(const float4* __restrict__ x,
                                             const float* __restrict__ mean,
                                             const float* __restrict__ varpart,
                                             const float* __restrict__ beta,
                                             const float* __restrict__ gamma,
                                             const float4* __restrict__ rowp,
                                             float4* __restrict__ out) {
    const int b   = blockIdx.x / BPB3;
    const int blk = blockIdx.x % BPB3;
    const int t   = threadIdx.x;
    const int c4  = t & 31;
    const int grp = t >> 5;
    const int row0 = blk * RPB3;

    __shared__ float4 abcd[RPB3];   // per-row output coefficients

    const float* meanb = mean + b * CCH;
    float4 mv = ((const float4*)meanb)[c4];
    float4 bv = ((const float4*)beta)[c4];
    float  b0 = beta[0];
    float  invb = __builtin_amdgcn_rcpf(1.0f + b0);

    float vsum = 0.f;
    #pragma unroll
    for (int k = 0; k < 32; ++k) vsum += varpart[(b << 5) + k];  // uniform
    float scale = gamma[0] * __builtin_amdgcn_rcpf(
                      vsum * (1.0f / (float)NROWS) + 1e-5f);

    // ---- stage: one row per thread (t < 128) ----
    if (t < RPB3) {
        float4 rp = rowp[(size_t)b * NROWS + row0 + t];
        float fac = rp.x, alpha = rp.y, tcv = rp.z, pb = rp.w;

        float F   = scale * fac;
        float TCv = scale * tcv;
        float SM  = fmaf(F, alpha, TCv);                 // scale * s_m
        float sq  = sqrtf(fmaxf(fmaf(alpha, alpha, -1.f), 1e-8f));
        float nu  = fmaxf(scale * (fac * sq), 1e-4f);    // = sqrt(clip(linner,1e-8))
        float PT  = scale * pb * invb;

        float ee = __expf(nu);
        float ei = __builtin_amdgcn_rcpf(ee);
        float ch = 0.5f * (ee + ei);
        float so = 0.5f * (ee - ei) * __builtin_amdgcn_rcpf(nu);

        abcd[t] = make_float4(so * F,                    // A
                              -so * SM,                  // B
                              fmaf(so, PT, ch),          // C
                              so * (PT - TCv));          // D (ch-0 add)
    }
    __syncthreads();

    const float4* xb = x + (size_t)b * NROWS * NC4;
    float4*       ob = out + (size_t)b * NROWS * NC4;

    #pragma unroll 4
    for (int r = grp; r < RPB3; r += 8) {
        float4 xv = xb[(size_t)(row0 + r) * NC4 + c4];
        float4 cf = abcd[r];                  // LDS broadcast within group
        float A = cf.x, B = cf.y, C = cf.z, D = cf.w;

        vf4 ov;
        ov.x = fmaf(A, xv.x, fmaf(B, mv.x, C * bv.x));
        ov.y = fmaf(A, xv.y, fmaf(B, mv.y, C * bv.y));
        ov.z = fmaf(A, xv.z, fmaf(B, mv.z, C * bv.z));
        ov.w = fmaf(A, xv.w, fmaf(B, mv.w, C * bv.w));
        if (c4 == 0) ov.x += D;
        // non-temporal full-line store: don't evict x from L3
        __builtin_nontemporal_store(ov, (vf4*)&ob[(size_t)(row0 + r) * NC4 + c4]);
    }
}

// ---------- launch ----------
extern "C" void kernel_launch(void* const* d_in, const int* in_sizes, int n_in,
                              void* d_out, int out_size, void* d_ws, size_t ws_size,
                              hipStream_t stream) {
    const float4* x     = (const float4*)d_in[0];
    const float*  beta  = (const float*)d_in[1];
    const float*  gamma = (const float*)d_in[2];
    float4*       out   = (float4*)d_out;

    // Workspace layout (all plain-stored, no memset required):
    //   part    [2048][128] floats : 1 MB     @ 0
    //   varpart [2048] floats      : 8 KB     @ 1 MB
    //   mean    [64][128] floats   : 32 KB    @ 1 MB + 8 KB
    //   rowp    [64*4096] float4   : 4 MB     @ 2 MB (16B aligned)
    char* wsb = (char*)d_ws;
    float*  part    = (float*)(wsb);
    float*  varpart = (float*)(wsb + (1 << 20));
    float*  mean    = (float*)(wsb + (1 << 20) + 8192);
    float4* rowp    = (float4*)(wsb + (2 << 20));

    k_sum<<<dim3(BSZ * BPB1), dim3(256), 0, stream>>>(x, part);
    k_rows<<<dim3(BSZ * BPB2), dim3(256), 0, stream>>>(
        x, part, beta, mean, varpart, rowp);
    k_out<<<dim3(BSZ * BPB3), dim3(256), 0, stream>>>(
        x, mean, varpart, beta, gamma, rowp, out);
}